// Round 15
// baseline (481.331 us; speedup 1.0000x reference)
//
#include <hip/hip_runtime.h>
#include <hip/hip_bf16.h>
#include <cstdint>
#include <cstddef>

// Problem constants
#define B_     16
#define HW_    4096
#define C_     256
#define NH_    8
#define S_     64
#define N_     64
#define C3_    768
#define HID_   1024
#define DHEAD_ 2048   // S*C/NH
#define EPS_   1e-5f

using u16 = unsigned short;
using u32 = unsigned int;

typedef __attribute__((ext_vector_type(8))) short bf16x8;
typedef __attribute__((ext_vector_type(4))) float f32x4;

__device__ __forceinline__ float bf2f(u16 u) {
  union { float f; u32 i; } x; x.i = ((u32)u) << 16; return x.f;
}
__device__ __forceinline__ u16 f2bf(float f) {
  union { float f; u32 i; } x; x.f = f;
  u32 r = (x.i + 0x7FFFu + ((x.i >> 16) & 1u)) >> 16;
  return (u16)r;
}

__device__ __forceinline__ void gload_lds16(const u16* g, u16* l) {
  __builtin_amdgcn_global_load_lds(
      (const __attribute__((address_space(1))) unsigned int*)g,
      (__attribute__((address_space(3))) unsigned int*)l, 16, 0, 0);
}

// ---------------------------------------------------------------------------
// Pack fp32 weight W[J][K] into MFMA B-fragment packets (bf16).
__launch_bounds__(256)
__global__ void pack_w_kernel(const float* __restrict__ W, u16* __restrict__ out,
                              int K, int kshift) {
  int g = blockIdx.x * 256 + threadIdx.x;
  int lane = g & 63;
  int pk = g >> 6;
  int cb = pk >> kshift;
  int kb = pk & ((1 << kshift) - 1);
  int j = cb * 16 + (lane & 15);
  int k = kb * 32 + ((lane >> 4) << 3);
  const float* src = W + (size_t)j * K + k;
  float4 a = ((const float4*)src)[0];
  float4 b = ((const float4*)src)[1];
  ushort4 lo = {f2bf(a.x), f2bf(a.y), f2bf(a.z), f2bf(a.w)};
  ushort4 hi = {f2bf(b.x), f2bf(b.y), f2bf(b.z), f2bf(b.w)};
  ushort4* dst = (ushort4*)(out + (size_t)g * 8);
  dst[0] = lo;
  dst[1] = hi;
}

// ---------------------------------------------------------------------------
// LayerNorm over C=256. One wave per token, 4 tokens/block. (LN1 only)
__launch_bounds__(256)
__global__ void ln_kernel(const float* __restrict__ in, const float* __restrict__ w,
                          const float* __restrict__ bias, u16* __restrict__ out,
                          int b_base) {
  int wave = threadIdx.x >> 6;
  int lane = threadIdx.x & 63;
  int t = blockIdx.x * 4 + wave;           // local token id
  int b = b_base + (t >> 12);
  int r = t & 4095;
  int n = r >> 6, s = r & 63;
  int hw = (((s >> 3) << 3) + (n >> 3)) * 64 + ((s & 7) << 3) + (n & 7);
  size_t src_row = ((size_t)b << 12) + hw;
  float4 v = ((const float4*)(in + src_row * C_))[lane];
  float sum = v.x + v.y + v.z + v.w;
#pragma unroll
  for (int off = 32; off; off >>= 1) sum += __shfl_xor(sum, off);
  float mean = sum * (1.0f / C_);
  float4 d = {v.x - mean, v.y - mean, v.z - mean, v.w - mean};
  float ss = d.x * d.x + d.y * d.y + d.z * d.z + d.w * d.w;
#pragma unroll
  for (int off = 32; off; off >>= 1) ss += __shfl_xor(ss, off);
  float rstd = rsqrtf(ss * (1.0f / C_) + EPS_);
  float4 w4 = ((const float4*)w)[lane];
  float4 b4 = ((const float4*)bias)[lane];
  ushort4 o;
  o.x = f2bf(d.x * rstd * w4.x + b4.x);
  o.y = f2bf(d.y * rstd * w4.y + b4.y);
  o.z = f2bf(d.z * rstd * w4.z + b4.z);
  o.w = f2bf(d.w * rstd * w4.w + b4.w);
  ((ushort4*)(out + (size_t)t * C_))[lane] = o;
}

// ---------------------------------------------------------------------------
// MFMA NT GEMM: round-9 loop + XCD chunked swizzle (T1) + LDS-staged
// coalesced epilogues for EPI 0/2.
// EPI 0: outB[m*J_+jj] = bf16(v)   (LDS-staged, bf16x8 vector stores)
// EPI 2: outF[(m_base+m)*C_+jj] += v (LDS-staged, float4 RMW)
// EPI 3: qkv scatter to head-major Qb/Kb + transposed Vt (scalar, unchanged)
template<int K_, int J_, int EPI>
__launch_bounds__(256)
__global__ void gemm_mfma(const u16* __restrict__ A, const u16* __restrict__ wpk,
                          const float* __restrict__ bias, u16* __restrict__ outB,
                          float* __restrict__ outF, const float* __restrict__ res,
                          int m_base, u16* __restrict__ qb, u16* __restrict__ kb,
                          u16* __restrict__ vt) {
  constexpr int NT = K_ / 64;
  __shared__ u16 As[2][128 * 64];   // 16 KB each (reused as epilogue staging)
  int tid = threadIdx.x;
  int wid = tid >> 6, lane = tid & 63;
  // XCD-aware chunked swizzle (nwg divisible by 8 for all launches here)
  int nx = gridDim.x;
  int bid = blockIdx.y * nx + blockIdx.x;
  int cpx = (nx * gridDim.y) >> 3;
  int swz = (bid & 7) * cpx + (bid >> 3);
  int n0 = (swz % nx) * 128;
  int m0 = (swz / nx) * 128;
  int wr = wid >> 1, wc = wid & 1;
  f32x4 acc[4][4] = {};
  int srow8 = lane >> 3, sslot = lane & 7;

#define ASTAGE(buf, t)                                                         \
  {                                                                            \
    int k0g = (t) * 64;                                                        \
    int cbb = ((sslot ^ srow8) << 4);                                          \
    _Pragma("unroll")                                                          \
    for (int r = 0; r < 4; ++r) {                                              \
      int row = wid * 32 + r * 8 + srow8;                                      \
      gload_lds16(A + (size_t)(m0 + row) * K_ + k0g + (cbb >> 1),              \
                  &As[buf][(wid * 32 + r * 8) * 64]);                          \
    }                                                                          \
  }

  ASTAGE(0, 0);
  asm volatile("s_waitcnt vmcnt(0)" ::: "memory");
  __builtin_amdgcn_sched_barrier(0);
  __builtin_amdgcn_s_barrier();
  __builtin_amdgcn_sched_barrier(0);

  for (int t = 0; t < NT; ++t) {
    bf16x8 bfr[8];
#pragma unroll
    for (int kk = 0; kk < 2; ++kk)
#pragma unroll
      for (int nf = 0; nf < 4; ++nf)
        bfr[kk * 4 + nf] = *(const bf16x8*)&wpk[
            ((size_t)(((n0 >> 4) + wc * 4 + nf) * (K_ / 32) + (t * 2 + kk)) * 64 + lane) * 8];
    if (t + 1 < NT) ASTAGE((t + 1) & 1, t + 1);
    const u16* as = As[t & 1];
#pragma unroll
    for (int kk = 0; kk < 2; ++kk) {
      bf16x8 afr[4];
#pragma unroll
      for (int mf = 0; mf < 4; ++mf) {
        int ra = wr * 64 + mf * 16 + (lane & 15);
        int cbb = (((kk * 4 + (lane >> 4)) ^ (ra & 7)) << 4);
        afr[mf] = *(const bf16x8*)&as[ra * 64 + (cbb >> 1)];
      }
#pragma unroll
      for (int mf = 0; mf < 4; ++mf)
#pragma unroll
        for (int nf = 0; nf < 4; ++nf)
          acc[mf][nf] = __builtin_amdgcn_mfma_f32_16x16x32_bf16(afr[mf], bfr[kk * 4 + nf], acc[mf][nf], 0, 0, 0);
    }
    asm volatile("s_waitcnt vmcnt(0)" ::: "memory");
    __builtin_amdgcn_sched_barrier(0);
    __builtin_amdgcn_s_barrier();
    __builtin_amdgcn_sched_barrier(0);
  }
#undef ASTAGE

  if (EPI == 0) {
    // LDS-staged coalesced store: two 64-row halves through As (dead).
    u16* ot = (u16*)As;               // stride 136 u16/row (272 B, ~2-way free)
#pragma unroll
    for (int half = 0; half < 2; ++half) {
      if (wr == half) {
#pragma unroll
        for (int nf = 0; nf < 4; ++nf) {
          int cloc = wc * 64 + nf * 16 + (lane & 15);
          float bv = bias[n0 + cloc];
#pragma unroll
          for (int mf = 0; mf < 4; ++mf)
#pragma unroll
            for (int j = 0; j < 4; ++j) {
              int rloc = mf * 16 + (lane >> 4) * 4 + j;
              ot[rloc * 136 + cloc] = f2bf(acc[mf][nf][j] + bv);
            }
        }
      }
      __syncthreads();
#pragma unroll
      for (int i = 0; i < 4; ++i) {
        int c = tid + 256 * i;
        int row = c >> 4, ch = c & 15;
        bf16x8 v = *(const bf16x8*)&ot[row * 136 + ch * 8];
        *(bf16x8*)&outB[(size_t)(m0 + half * 64 + row) * J_ + n0 + ch * 8] = v;
      }
      __syncthreads();
    }
  } else if (EPI == 2) {
    // LDS-staged float4 RMW: four 32-row quarters through As.
    float* ot32 = (float*)As;         // stride 132 f32/row (528 B)
#pragma unroll
    for (int q = 0; q < 4; ++q) {
      if (wr == (q >> 1)) {
        int mfb = (q & 1) * 2;
#pragma unroll
        for (int nf = 0; nf < 4; ++nf) {
          int cloc = wc * 64 + nf * 16 + (lane & 15);
          float bv = bias[n0 + cloc];
#pragma unroll
          for (int mf2 = 0; mf2 < 2; ++mf2)
#pragma unroll
            for (int j = 0; j < 4; ++j) {
              int rloc = mf2 * 16 + (lane >> 4) * 4 + j;
              ot32[rloc * 132 + cloc] = acc[mfb + mf2][nf][j] + bv;
            }
        }
      }
      __syncthreads();
#pragma unroll
      for (int i = 0; i < 4; ++i) {
        int c = tid + 256 * i;
        int row = c >> 5, ch = c & 31;
        size_t o = (size_t)(m_base + m0 + q * 32 + row) * C_ + n0 + ch * 4;
        float4 cur = *(const float4*)&outF[o];
        float4 ad = *(const float4*)&ot32[row * 132 + ch * 4];
        cur.x += ad.x; cur.y += ad.y; cur.z += ad.z; cur.w += ad.w;
        *(float4*)&outF[o] = cur;
      }
      __syncthreads();
    }
  } else {
    // EPI 3: qkv scatter (scalar — destinations inherently strided)
#pragma unroll
    for (int nf = 0; nf < 4; ++nf) {
      int col = n0 + wc * 64 + nf * 16 + (lane & 15);
      float bv = bias[col];
#pragma unroll
      for (int mf = 0; mf < 4; ++mf) {
#pragma unroll
        for (int j = 0; j < 4; ++j) {
          int m = m0 + wr * 64 + mf * 16 + (lane >> 4) * 4 + j;
          float v = acc[mf][nf][j] + bv;
          int b_rel = m >> 12, nn = (m >> 6) & 63, s = m & 63;
          int f = s * 768 + col;
          int part = f >> 14, hh = (f >> 11) & 7, d = f & 2047;
          u16 val = f2bf(v);
          size_t bh = (size_t)b_rel * 8 + hh;
          if (part == 0)      qb[(bh * 64 + nn) * 2048 + d] = val;
          else if (part == 1) kb[(bh * 64 + nn) * 2048 + d] = val;
          else                vt[(bh * 2048 + d) * 64 + nn] = val;
        }
      }
    }
  }
}

// ---------------------------------------------------------------------------
// Fused proj GEMM + residual + LayerNorm2 (round-9 structure).
__launch_bounds__(256)
__global__ void proj_ln_fused(const u16* __restrict__ A, const u16* __restrict__ wpk,
                              const float* __restrict__ bias, const float* __restrict__ res,
                              float* __restrict__ outF, const float* __restrict__ ln_w,
                              const float* __restrict__ ln_b, u16* __restrict__ h2,
                              int m_base) {
  __shared__ u16 As[2][64 * 64];    // 8 KB each
  __shared__ float red[64][8];
  int tid = threadIdx.x;
  int wid = tid >> 6, lane = tid & 63;
  int m0 = blockIdx.x * 64;
  f32x4 acc[4][4] = {};             // [mf(row)][nf(col)]
  int srow8 = lane >> 3, sslot = lane & 7;

#define PSTAGE(buf, t)                                                         \
  {                                                                            \
    int k0g = (t) * 64;                                                        \
    int cbb = ((sslot ^ srow8) << 4);                                          \
    _Pragma("unroll")                                                          \
    for (int r = 0; r < 2; ++r) {                                              \
      int row = wid * 16 + r * 8 + srow8;                                      \
      gload_lds16(A + (size_t)(m0 + row) * 256 + k0g + (cbb >> 1),             \
                  &As[buf][(wid * 16 + r * 8) * 64]);                          \
    }                                                                          \
  }

  PSTAGE(0, 0);
  asm volatile("s_waitcnt vmcnt(0)" ::: "memory");
  __builtin_amdgcn_sched_barrier(0);
  __builtin_amdgcn_s_barrier();
  __builtin_amdgcn_sched_barrier(0);

#pragma unroll
  for (int t = 0; t < 4; ++t) {
    bf16x8 bfr[8];
#pragma unroll
    for (int kk = 0; kk < 2; ++kk)
#pragma unroll
      for (int nf = 0; nf < 4; ++nf)
        bfr[kk * 4 + nf] = *(const bf16x8*)&wpk[
            ((size_t)((wid * 4 + nf) * 8 + (t * 2 + kk)) * 64 + lane) * 8];
    if (t + 1 < 4) PSTAGE((t + 1) & 1, t + 1);
    const u16* as = As[t & 1];
#pragma unroll
    for (int kk = 0; kk < 2; ++kk) {
      bf16x8 afr[4];
#pragma unroll
      for (int mf = 0; mf < 4; ++mf) {
        int ra = mf * 16 + (lane & 15);
        int cbb = (((kk * 4 + (lane >> 4)) ^ (ra & 7)) << 4);
        afr[mf] = *(const bf16x8*)&as[ra * 64 + (cbb >> 1)];
      }
#pragma unroll
      for (int mf = 0; mf < 4; ++mf)
#pragma unroll
        for (int nf = 0; nf < 4; ++nf)
          acc[mf][nf] = __builtin_amdgcn_mfma_f32_16x16x32_bf16(afr[mf], bfr[kk * 4 + nf], acc[mf][nf], 0, 0, 0);
    }
    asm volatile("s_waitcnt vmcnt(0)" ::: "memory");
    __builtin_amdgcn_sched_barrier(0);
    __builtin_amdgcn_s_barrier();
    __builtin_amdgcn_sched_barrier(0);
  }
#undef PSTAGE

  // residual + bias; write d_out; accumulate LN partials
#pragma unroll
  for (int mf = 0; mf < 4; ++mf) {
#pragma unroll
    for (int j = 0; j < 4; ++j) {
      int m = m0 + mf * 16 + (lane >> 4) * 4 + j;
      int gm = m_base + m;
      int b = gm >> 12, nn = (gm >> 6) & 63, s = gm & 63;
      int hw = (((s >> 3) << 3) + (nn >> 3)) * 64 + ((s & 7) << 3) + (nn & 7);
      size_t rowo = (((size_t)b << 12) + hw) * C_;
      float s1 = 0.f, s2 = 0.f;
#pragma unroll
      for (int nf = 0; nf < 4; ++nf) {
        int col = wid * 64 + nf * 16 + (lane & 15);
        float v = acc[mf][nf][j] + bias[col] + res[rowo + col];
        acc[mf][nf][j] = v;
        outF[rowo + col] = v;
        s1 += v; s2 += v * v;
      }
#pragma unroll
      for (int off = 1; off < 16; off <<= 1) {
        s1 += __shfl_xor(s1, off);
        s2 += __shfl_xor(s2, off);
      }
      if ((lane & 15) == 0) {
        int rr = mf * 16 + (lane >> 4) * 4 + j;
        red[rr][wid * 2] = s1;
        red[rr][wid * 2 + 1] = s2;
      }
    }
  }
  __syncthreads();

  // finish LN, write h2 bf16 (row = local token (b_rel, hw))
#pragma unroll
  for (int mf = 0; mf < 4; ++mf) {
#pragma unroll
    for (int j = 0; j < 4; ++j) {
      int rr = mf * 16 + (lane >> 4) * 4 + j;
      float sum = red[rr][0] + red[rr][2] + red[rr][4] + red[rr][6];
      float ssq = red[rr][1] + red[rr][3] + red[rr][5] + red[rr][7];
      float mean = sum * (1.0f / C_);
      float var = ssq * (1.0f / C_) - mean * mean;
      float rstd = rsqrtf(var + EPS_);
      int m = m0 + rr;
      int b_rel = m >> 12, nn = (m >> 6) & 63, s = m & 63;
      int hw = (((s >> 3) << 3) + (nn >> 3)) * 64 + ((s & 7) << 3) + (nn & 7);
      size_t ho = (((size_t)b_rel << 12) + hw) * C_;
#pragma unroll
      for (int nf = 0; nf < 4; ++nf) {
        int col = wid * 64 + nf * 16 + (lane & 15);
        float nv = (acc[mf][nf][j] - mean) * rstd * ln_w[col] + ln_b[col];
        h2[ho + col] = f2bf(nv);
      }
    }
  }
}

// ---------------------------------------------------------------------------
// MFMA attention, d0-split + chunked XCD swizzle (pair (bh,0)/(bh,1) co-resides
// on one XCD so shared Q/K reads are L2-hits).
__launch_bounds__(256)
__global__ void attn_mfma(const u16* __restrict__ qb, const u16* __restrict__ kb,
                          const u16* __restrict__ vt, const float* __restrict__ rel_bias,
                          u16* __restrict__ outp) {
  __shared__ u16 bufA[4096];   // Q tile, then P
  __shared__ u16 bufB[4096];   // K tile, then V tile
  int nb = gridDim.x;
  int cpx = nb >> 3;
  int swzb = (blockIdx.x & 7) * cpx + (blockIdx.x >> 3);
  int half = swzb & 1;
  int bh = swzb >> 1;          // b_rel*8 + h
  int h = bh & 7;
  int b_rel = bh >> 3;
  int tid = threadIdx.x;
  int w = tid >> 6, lane = tid & 63;
  int l3 = lane >> 3, l7 = lane & 7;
  const u16* qg = qb + (size_t)bh * 64 * 2048;
  const u16* kg = kb + (size_t)bh * 64 * 2048;
  const u16* vg = vt + (size_t)bh * 2048 * 64;

  // ---- phase 1: S = Q K^T ----
  f32x4 acc[4] = {};
  for (int k0 = 0; k0 < 2048; k0 += 64) {
#pragma unroll
    for (int r = 0; r < 2; ++r) {
      int row = w * 16 + r * 8 + l3;
      int sc = (l7 ^ (row & 7)) * 8;
      gload_lds16(qg + (size_t)row * 2048 + k0 + sc, &bufA[(w * 16 + r * 8) * 64]);
      gload_lds16(kg + (size_t)row * 2048 + k0 + sc, &bufB[(w * 16 + r * 8) * 64]);
    }
    __syncthreads();
    int rowq = w * 16 + (lane & 15);
#pragma unroll
    for (int ks = 0; ks < 2; ++ks) {
      bf16x8 aq = *(const bf16x8*)&bufA[rowq * 64 + (((ks * 4 + (lane >> 4)) ^ (rowq & 7)) << 3)];
#pragma unroll
      for (int cf = 0; cf < 4; ++cf) {
        int m = cf * 16 + (lane & 15);
        bf16x8 bk = *(const bf16x8*)&bufB[m * 64 + (((ks * 4 + (lane >> 4)) ^ (m & 7)) << 3)];
        acc[cf] = __builtin_amdgcn_mfma_f32_16x16x32_bf16(aq, bk, acc[cf], 0, 0, 0);
      }
    }
    __syncthreads();
  }

  // ---- phase 2: scale + rel bias + softmax ----
  const float scale = 0.17677669529663688f;   // 1/sqrt(32)
#pragma unroll
  for (int j = 0; j < 4; ++j) {
    int r = w * 16 + (lane >> 4) * 4 + j;
    int i1 = r >> 3, j1 = r & 7;
    float v[4];
#pragma unroll
    for (int cf = 0; cf < 4; ++cf) {
      int c = cf * 16 + (lane & 15);
      int idx = (i1 - (c >> 3) + 7) * 15 + (j1 - (c & 7) + 7);
      v[cf] = acc[cf][j] * scale + rel_bias[idx * NH_ + h];
    }
    float mx = fmaxf(fmaxf(v[0], v[1]), fmaxf(v[2], v[3]));
#pragma unroll
    for (int off = 8; off; off >>= 1) mx = fmaxf(mx, __shfl_xor(mx, off));
    float sm = 0.f;
#pragma unroll
    for (int cf = 0; cf < 4; ++cf) { v[cf] = __expf(v[cf] - mx); sm += v[cf]; }
#pragma unroll
    for (int off = 8; off; off >>= 1) sm += __shfl_xor(sm, off);
    float inv = 1.0f / sm;
#pragma unroll
    for (int cf = 0; cf < 4; ++cf) {
      int c = cf * 16 + (lane & 15);
      bufA[r * 64 + (c ^ ((r & 7) << 3))] = f2bf(v[cf] * inv);
    }
  }
  __syncthreads();

  bf16x8 pa[2];
  {
    int n = w * 16 + (lane & 15);
#pragma unroll
    for (int ks = 0; ks < 2; ++ks)
      pa[ks] = *(const bf16x8*)&bufA[n * 64 + ((ks * 32 + (lane >> 4) * 8) ^ ((n & 7) << 3))];
  }

  // ---- phase 3: O = P V (this block's d0 half only) ----
  int d0beg = half * 1024;
  for (int d0 = d0beg; d0 < d0beg + 1024; d0 += 64) {
#pragma unroll
    for (int r = 0; r < 2; ++r) {
      int drow = w * 16 + r * 8 + l3;
      int sc = (l7 ^ (drow & 7)) * 8;
      gload_lds16(vg + (size_t)(d0 + drow) * 64 + sc, &bufB[(w * 16 + r * 8) * 64]);
    }
    __syncthreads();
    f32x4 o[4] = {};
#pragma unroll
    for (int ks = 0; ks < 2; ++ks)
#pragma unroll
      for (int cf = 0; cf < 4; ++cf) {
        int d = cf * 16 + (lane & 15);
        bf16x8 bv = *(const bf16x8*)&bufB[d * 64 + (((ks * 4 + (lane >> 4)) ^ (d & 7)) << 3)];
        o[cf] = __builtin_amdgcn_mfma_f32_16x16x32_bf16(pa[ks], bv, o[cf], 0, 0, 0);
      }
#pragma unroll
    for (int cf = 0; cf < 4; ++cf) {
      int f = h * 2048 + d0 + cf * 16 + (lane & 15);
      int s = f >> 8, c = f & 255;
#pragma unroll
      for (int j = 0; j < 4; ++j) {
        int n = w * 16 + (lane >> 4) * 4 + j;
        outp[(((size_t)b_rel * 64 + n) * 64 + s) * 256 + c] = f2bf(o[cf][j]);
      }
    }
    __syncthreads();
  }
}

// ---------------------------------------------------------------------------
// Depthwise 3x3 SAME + bias + exact GELU — 4x2 pixel register tile + chunked
// XCD swizzle (adjacent tiles share halo rows -> L2 locality).
__launch_bounds__(256)
__global__ void dwconv_gelu(const u16* __restrict__ y1, const float* __restrict__ dw_w,
                            const float* __restrict__ dw_b, u16* __restrict__ y2) {
  int nb = gridDim.x;
  int cpx = nb >> 3;
  int bid = (blockIdx.x & 7) * cpx + (blockIdx.x >> 3);
  int wt = bid & 31, ht = (bid >> 5) & 15, b = bid >> 9;
  int h0 = ht * 4, w0 = wt * 2;
  int c0 = threadIdx.x * 4;

  float4 wv[9];
#pragma unroll
  for (int i = 0; i < 9; ++i) wv[i] = *(const float4*)&dw_w[i * HID_ + c0];

  ushort4 in[6][4];
#pragma unroll
  for (int ii = 0; ii < 6; ++ii) {
    int hh = h0 + ii - 1;
#pragma unroll
    for (int jj = 0; jj < 4; ++jj) {
      int ww = w0 + jj - 1;
      if ((unsigned)hh < 64u && (unsigned)ww < 64u)
        in[ii][jj] = *(const ushort4*)(y1 + ((size_t)((b << 12) + hh * 64 + ww)) * HID_ + c0);
      else
        in[ii][jj] = ushort4{0, 0, 0, 0};
    }
  }

  float4 bv = *(const float4*)&dw_b[c0];
  float4 acc[4][2];
#pragma unroll
  for (int i = 0; i < 4; ++i)
#pragma unroll
    for (int j = 0; j < 2; ++j) acc[i][j] = bv;

#pragma unroll
  for (int ii = 0; ii < 6; ++ii) {
#pragma unroll
    for (int jj = 0; jj < 4; ++jj) {
      ushort4 u = in[ii][jj];
      float4 f = {bf2f(u.x), bf2f(u.y), bf2f(u.z), bf2f(u.w)};
#pragma unroll
      for (int kh = 0; kh < 3; ++kh) {
        int i = ii - kh;
        if (i < 0 || i > 3) continue;
#pragma unroll
        for (int kw = 0; kw < 3; ++kw) {
          int j = jj - kw;
          if (j < 0 || j > 1) continue;
          float4 w4 = wv[kh * 3 + kw];
          acc[i][j].x += f.x * w4.x;
          acc[i][j].y += f.y * w4.y;
          acc[i][j].z += f.z * w4.z;
          acc[i][j].w += f.w * w4.w;
        }
      }
    }
  }

  const float k = 0.70710678118654752f;
#pragma unroll
  for (int i = 0; i < 4; ++i) {
#pragma unroll
    for (int j = 0; j < 2; ++j) {
      float4 a = acc[i][j];
      ushort4 o;
      o.x = f2bf(0.5f * a.x * (1.0f + erff(a.x * k)));
      o.y = f2bf(0.5f * a.y * (1.0f + erff(a.y * k)));
      o.z = f2bf(0.5f * a.z * (1.0f + erff(a.z * k)));
      o.w = f2bf(0.5f * a.w * (1.0f + erff(a.w * k)));
      *(ushort4*)(y2 + ((size_t)((b << 12) + (h0 + i) * 64 + (w0 + j))) * HID_ + c0) = o;
    }
  }
}

// ---------------------------------------------------------------------------
extern "C" void kernel_launch(void* const* d_in, const int* in_sizes, int n_in,
                              void* d_out, int out_size, void* d_ws, size_t ws_size,
                              hipStream_t stream) {
  const float* x       = (const float*)d_in[0];
  const float* norm1_w = (const float*)d_in[1];
  const float* norm1_b = (const float*)d_in[2];
  const float* qkv_w   = (const float*)d_in[3];
  const float* qkv_b   = (const float*)d_in[4];
  const float* rel_b   = (const float*)d_in[5];
  const float* proj_w  = (const float*)d_in[6];
  const float* proj_b  = (const float*)d_in[7];
  const float* norm2_w = (const float*)d_in[8];
  const float* norm2_b = (const float*)d_in[9];
  const float* fc1_w   = (const float*)d_in[10];
  const float* fc1_b   = (const float*)d_in[11];
  const float* dw_w    = (const float*)d_in[12];
  const float* dw_b    = (const float*)d_in[13];
  const float* fc2_w   = (const float*)d_in[14];
  const float* fc2_b   = (const float*)d_in[15];
  float* out = (float*)d_out;
  char* ws = (char*)d_ws;

  // --- packed-weight slab: first 2 MB of ws ---
  u16* wq = (u16*)(ws);                       // 768*256
  u16* wp = wq + 768 * 256;                   // 256*256
  u16* w1 = wp + 256 * 256;                   // 1024*256
  u16* w2 = w1 + 1024 * 256;                  // 256*1024
  pack_w_kernel<<<768 * 256 / 8 / 256, 256, 0, stream>>>(qkv_w, wq, 256, 3);
  pack_w_kernel<<<256 * 256 / 8 / 256, 256, 0, stream>>>(proj_w, wp, 256, 3);
  pack_w_kernel<<<1024 * 256 / 8 / 256, 256, 0, stream>>>(fc1_w, w1, 256, 3);
  pack_w_kernel<<<256 * 1024 / 8 / 256, 256, 0, stream>>>(fc2_w, w2, 1024, 5);

  // --- adaptive chunking over batches; chunk workspace = 18*G MB after 2 MB ---
  const size_t MBy = (size_t)1 << 20;
  char* cws = ws + 2 * MBy;
  int G = 1;
  for (int g = 16; g >= 1; g >>= 1) {
    if (2 * MBy + (size_t)(18 * g) * MBy <= ws_size) { G = g; break; }
  }
  const size_t gm = (size_t)G * MBy;
  u16* h1c    = (u16*)(cws);                 // 2G MB
  u16* qbuf   = (u16*)(cws + 2 * gm);        // 2G MB  [bh][n][2048]
  u16* kbuf   = (u16*)(cws + 4 * gm);        // 2G MB  [bh][m][2048]
  u16* vtbuf  = (u16*)(cws + 6 * gm);        // 2G MB  [bh][d][64]
  u16* attnoc = (u16*)(cws + 8 * gm);        // 2G MB
  u16* h2c    = (u16*)(cws);                 // 2G MB (over dead h1c)
  u16* y1c    = (u16*)(cws + 2 * gm);        // 8G MB (over dead q/k/vt)
  u16* y2c    = (u16*)(cws + 10 * gm);       // 8G MB

  const int Mloc = G * 4096;
  for (int b0 = 0; b0 < B_; b0 += G) {
    ln_kernel<<<Mloc / 4, 256, 0, stream>>>(x, norm1_w, norm1_b, h1c, b0);
    gemm_mfma<256, 768, 3><<<dim3(6, Mloc / 128), 256, 0, stream>>>(
        h1c, wq, qkv_b, nullptr, nullptr, nullptr, 0, qbuf, kbuf, vtbuf);
    attn_mfma<<<G * 16, 256, 0, stream>>>(qbuf, kbuf, vtbuf, rel_b, attnoc);
    proj_ln_fused<<<Mloc / 64, 256, 0, stream>>>(
        attnoc, wp, proj_b, x, out, norm2_w, norm2_b, h2c, b0 * 4096);
    gemm_mfma<256, 1024, 0><<<dim3(8, Mloc / 128), 256, 0, stream>>>(
        h2c, w1, fc1_b, y1c, nullptr, nullptr, 0, nullptr, nullptr, nullptr);
    dwconv_gelu<<<Mloc / 8, 256, 0, stream>>>(y1c, dw_w, dw_b, y2c);
    gemm_mfma<1024, 256, 2><<<dim3(2, Mloc / 128), 256, 0, stream>>>(
        y2c, w2, fc2_b, nullptr, out, nullptr, b0 * 4096, nullptr, nullptr, nullptr);
  }
}

// Round 16
// 468.895 us; speedup vs baseline: 1.0265x; 1.0265x over previous
//
#include <hip/hip_runtime.h>
#include <hip/hip_bf16.h>
#include <cstdint>
#include <cstddef>

// Problem constants
#define B_     16
#define HW_    4096
#define C_     256
#define NH_    8
#define S_     64
#define N_     64
#define C3_    768
#define HID_   1024
#define DHEAD_ 2048   // S*C/NH
#define EPS_   1e-5f

using u16 = unsigned short;
using u32 = unsigned int;

typedef __attribute__((ext_vector_type(8))) short bf16x8;
typedef __attribute__((ext_vector_type(4))) float f32x4;

__device__ __forceinline__ float bf2f(u16 u) {
  union { float f; u32 i; } x; x.i = ((u32)u) << 16; return x.f;
}
__device__ __forceinline__ u16 f2bf(float f) {
  union { float f; u32 i; } x; x.f = f;
  u32 r = (x.i + 0x7FFFu + ((x.i >> 16) & 1u)) >> 16;
  return (u16)r;
}

__device__ __forceinline__ void gload_lds16(const u16* g, u16* l) {
  __builtin_amdgcn_global_load_lds(
      (const __attribute__((address_space(1))) unsigned int*)g,
      (__attribute__((address_space(3))) unsigned int*)l, 16, 0, 0);
}

// ---------------------------------------------------------------------------
// Pack fp32 weight W[J][K] into MFMA B-fragment packets (bf16).
__launch_bounds__(256)
__global__ void pack_w_kernel(const float* __restrict__ W, u16* __restrict__ out,
                              int K, int kshift) {
  int g = blockIdx.x * 256 + threadIdx.x;
  int lane = g & 63;
  int pk = g >> 6;
  int cb = pk >> kshift;
  int kb = pk & ((1 << kshift) - 1);
  int j = cb * 16 + (lane & 15);
  int k = kb * 32 + ((lane >> 4) << 3);
  const float* src = W + (size_t)j * K + k;
  float4 a = ((const float4*)src)[0];
  float4 b = ((const float4*)src)[1];
  ushort4 lo = {f2bf(a.x), f2bf(a.y), f2bf(a.z), f2bf(a.w)};
  ushort4 hi = {f2bf(b.x), f2bf(b.y), f2bf(b.z), f2bf(b.w)};
  ushort4* dst = (ushort4*)(out + (size_t)g * 8);
  dst[0] = lo;
  dst[1] = hi;
}

// ---------------------------------------------------------------------------
// LayerNorm over C=256. One wave per token, 4 tokens/block. (LN1 only)
__launch_bounds__(256)
__global__ void ln_kernel(const float* __restrict__ in, const float* __restrict__ w,
                          const float* __restrict__ bias, u16* __restrict__ out,
                          int b_base) {
  int wave = threadIdx.x >> 6;
  int lane = threadIdx.x & 63;
  int t = blockIdx.x * 4 + wave;           // local token id
  int b = b_base + (t >> 12);
  int r = t & 4095;
  int n = r >> 6, s = r & 63;
  int hw = (((s >> 3) << 3) + (n >> 3)) * 64 + ((s & 7) << 3) + (n & 7);
  size_t src_row = ((size_t)b << 12) + hw;
  float4 v = ((const float4*)(in + src_row * C_))[lane];
  float sum = v.x + v.y + v.z + v.w;
#pragma unroll
  for (int off = 32; off; off >>= 1) sum += __shfl_xor(sum, off);
  float mean = sum * (1.0f / C_);
  float4 d = {v.x - mean, v.y - mean, v.z - mean, v.w - mean};
  float ss = d.x * d.x + d.y * d.y + d.z * d.z + d.w * d.w;
#pragma unroll
  for (int off = 32; off; off >>= 1) ss += __shfl_xor(ss, off);
  float rstd = rsqrtf(ss * (1.0f / C_) + EPS_);
  float4 w4 = ((const float4*)w)[lane];
  float4 b4 = ((const float4*)bias)[lane];
  ushort4 o;
  o.x = f2bf(d.x * rstd * w4.x + b4.x);
  o.y = f2bf(d.y * rstd * w4.y + b4.y);
  o.z = f2bf(d.z * rstd * w4.z + b4.z);
  o.w = f2bf(d.w * rstd * w4.w + b4.w);
  ((ushort4*)(out + (size_t)t * C_))[lane] = o;
}

// ---------------------------------------------------------------------------
// MFMA NT GEMM: XCD chunked swizzle + TRIPLE-buffered A staging with COUNTED
// vmcnt (T4): one barrier per K-step, loads stay in flight across it.
//   per step t: {bfr(t) loads ; vmcnt(8) ; barrier ; ASTAGE(t+2) ; MFMA(t)}
// Race audit: stage(t+2) writes buf[(t+2)%3], last read in step t-1 (ended
// before this step's barrier). vmcnt(8): the only ops allowed outstanding at
// the barrier are the 8 bfr(t) loads -> stage(t)/(t+1) proven landed.
// EPI 0: outB = bf16 (LDS-staged vector stores)
// EPI 2: outF += v  (LDS-staged float4 RMW)
// EPI 3: qkv scatter to head-major Qb/Kb + transposed Vt
template<int K_, int J_, int EPI>
__launch_bounds__(256)
__global__ void gemm_mfma(const u16* __restrict__ A, const u16* __restrict__ wpk,
                          const float* __restrict__ bias, u16* __restrict__ outB,
                          float* __restrict__ outF, const float* __restrict__ res,
                          int m_base, u16* __restrict__ qb, u16* __restrict__ kb,
                          u16* __restrict__ vt) {
  constexpr int NT = K_ / 64;
  __shared__ u16 As[3][128 * 64];   // 16 KB each (triple buffer, 48 KB)
  int tid = threadIdx.x;
  int wid = tid >> 6, lane = tid & 63;
  // XCD-aware chunked swizzle (nwg divisible by 8 for all launches here)
  int nx = gridDim.x;
  int bid = blockIdx.y * nx + blockIdx.x;
  int cpx = (nx * gridDim.y) >> 3;
  int swz = (bid & 7) * cpx + (bid >> 3);
  int n0 = (swz % nx) * 128;
  int m0 = (swz / nx) * 128;
  int wr = wid >> 1, wc = wid & 1;
  f32x4 acc[4][4] = {};
  int srow8 = lane >> 3, sslot = lane & 7;

#define ASTAGE(buf, t)                                                         \
  {                                                                            \
    int k0g = (t) * 64;                                                        \
    int cbb = ((sslot ^ srow8) << 4);                                          \
    _Pragma("unroll")                                                          \
    for (int r = 0; r < 4; ++r) {                                              \
      int row = wid * 32 + r * 8 + srow8;                                      \
      gload_lds16(A + (size_t)(m0 + row) * K_ + k0g + (cbb >> 1),              \
                  &As[buf][(wid * 32 + r * 8) * 64]);                          \
    }                                                                          \
  }

  ASTAGE(0, 0);
  ASTAGE(1, 1);

  for (int t = 0; t < NT; ++t) {
    // B fragments for this step (8 loads; these cross the barrier in flight)
    bf16x8 bfr[8];
#pragma unroll
    for (int kk = 0; kk < 2; ++kk)
#pragma unroll
      for (int nf = 0; nf < 4; ++nf)
        bfr[kk * 4 + nf] = *(const bf16x8*)&wpk[
            ((size_t)(((n0 >> 4) + wc * 4 + nf) * (K_ / 32) + (t * 2 + kk)) * 64 + lane) * 8];
    // counted wait: everything older than the 8 bfr loads (i.e. stage(t),
    // stage(t+1)) has landed; bfr stays outstanding across the barrier.
    asm volatile("s_waitcnt vmcnt(8)" ::: "memory");
    __builtin_amdgcn_sched_barrier(0);
    __builtin_amdgcn_s_barrier();
    __builtin_amdgcn_sched_barrier(0);
    if (t + 2 < NT) ASTAGE((t + 2) % 3, t + 2);
    const u16* as = As[t % 3];
#pragma unroll
    for (int kk = 0; kk < 2; ++kk) {
      bf16x8 afr[4];
#pragma unroll
      for (int mf = 0; mf < 4; ++mf) {
        int ra = wr * 64 + mf * 16 + (lane & 15);
        int cbb = (((kk * 4 + (lane >> 4)) ^ (ra & 7)) << 4);
        afr[mf] = *(const bf16x8*)&as[ra * 64 + (cbb >> 1)];
      }
#pragma unroll
      for (int mf = 0; mf < 4; ++mf)
#pragma unroll
        for (int nf = 0; nf < 4; ++nf)
          acc[mf][nf] = __builtin_amdgcn_mfma_f32_16x16x32_bf16(afr[mf], bfr[kk * 4 + nf], acc[mf][nf], 0, 0, 0);
    }
  }
#undef ASTAGE

  if (EPI == 0) {
    __syncthreads();                  // As reused as staging; drain last reads
    // LDS-staged coalesced store: two 64-row halves through As.
    u16* ot = (u16*)As;               // stride 136 u16/row
#pragma unroll
    for (int half = 0; half < 2; ++half) {
      if (wr == half) {
#pragma unroll
        for (int nf = 0; nf < 4; ++nf) {
          int cloc = wc * 64 + nf * 16 + (lane & 15);
          float bv = bias[n0 + cloc];
#pragma unroll
          for (int mf = 0; mf < 4; ++mf)
#pragma unroll
            for (int j = 0; j < 4; ++j) {
              int rloc = mf * 16 + (lane >> 4) * 4 + j;
              ot[rloc * 136 + cloc] = f2bf(acc[mf][nf][j] + bv);
            }
        }
      }
      __syncthreads();
#pragma unroll
      for (int i = 0; i < 4; ++i) {
        int c = tid + 256 * i;
        int row = c >> 4, ch = c & 15;
        bf16x8 v = *(const bf16x8*)&ot[row * 136 + ch * 8];
        *(bf16x8*)&outB[(size_t)(m0 + half * 64 + row) * J_ + n0 + ch * 8] = v;
      }
      __syncthreads();
    }
  } else if (EPI == 2) {
    __syncthreads();
    // LDS-staged float4 RMW: four 32-row quarters through As.
    float* ot32 = (float*)As;         // stride 132 f32/row
#pragma unroll
    for (int q = 0; q < 4; ++q) {
      if (wr == (q >> 1)) {
        int mfb = (q & 1) * 2;
#pragma unroll
        for (int nf = 0; nf < 4; ++nf) {
          int cloc = wc * 64 + nf * 16 + (lane & 15);
          float bv = bias[n0 + cloc];
#pragma unroll
          for (int mf2 = 0; mf2 < 2; ++mf2)
#pragma unroll
            for (int j = 0; j < 4; ++j) {
              int rloc = mf2 * 16 + (lane >> 4) * 4 + j;
              ot32[rloc * 132 + cloc] = acc[mfb + mf2][nf][j] + bv;
            }
        }
      }
      __syncthreads();
#pragma unroll
      for (int i = 0; i < 4; ++i) {
        int c = tid + 256 * i;
        int row = c >> 5, ch = c & 31;
        size_t o = (size_t)(m_base + m0 + q * 32 + row) * C_ + n0 + ch * 4;
        float4 cur = *(const float4*)&outF[o];
        float4 ad = *(const float4*)&ot32[row * 132 + ch * 4];
        cur.x += ad.x; cur.y += ad.y; cur.z += ad.z; cur.w += ad.w;
        *(float4*)&outF[o] = cur;
      }
      __syncthreads();
    }
  } else {
    // EPI 3: qkv scatter (scalar — destinations inherently strided)
#pragma unroll
    for (int nf = 0; nf < 4; ++nf) {
      int col = n0 + wc * 64 + nf * 16 + (lane & 15);
      float bv = bias[col];
#pragma unroll
      for (int mf = 0; mf < 4; ++mf) {
#pragma unroll
        for (int j = 0; j < 4; ++j) {
          int m = m0 + wr * 64 + mf * 16 + (lane >> 4) * 4 + j;
          float v = acc[mf][nf][j] + bv;
          int b_rel = m >> 12, nn = (m >> 6) & 63, s = m & 63;
          int f = s * 768 + col;
          int part = f >> 14, hh = (f >> 11) & 7, d = f & 2047;
          u16 val = f2bf(v);
          size_t bh = (size_t)b_rel * 8 + hh;
          if (part == 0)      qb[(bh * 64 + nn) * 2048 + d] = val;
          else if (part == 1) kb[(bh * 64 + nn) * 2048 + d] = val;
          else                vt[(bh * 2048 + d) * 64 + nn] = val;
        }
      }
    }
  }
}

// ---------------------------------------------------------------------------
// Fused proj GEMM + residual + LayerNorm2 (round-9 structure, unchanged).
__launch_bounds__(256)
__global__ void proj_ln_fused(const u16* __restrict__ A, const u16* __restrict__ wpk,
                              const float* __restrict__ bias, const float* __restrict__ res,
                              float* __restrict__ outF, const float* __restrict__ ln_w,
                              const float* __restrict__ ln_b, u16* __restrict__ h2,
                              int m_base) {
  __shared__ u16 As[2][64 * 64];    // 8 KB each
  __shared__ float red[64][8];
  int tid = threadIdx.x;
  int wid = tid >> 6, lane = tid & 63;
  int m0 = blockIdx.x * 64;
  f32x4 acc[4][4] = {};             // [mf(row)][nf(col)]
  int srow8 = lane >> 3, sslot = lane & 7;

#define PSTAGE(buf, t)                                                         \
  {                                                                            \
    int k0g = (t) * 64;                                                        \
    int cbb = ((sslot ^ srow8) << 4);                                          \
    _Pragma("unroll")                                                          \
    for (int r = 0; r < 2; ++r) {                                              \
      int row = wid * 16 + r * 8 + srow8;                                      \
      gload_lds16(A + (size_t)(m0 + row) * 256 + k0g + (cbb >> 1),             \
                  &As[buf][(wid * 16 + r * 8) * 64]);                          \
    }                                                                          \
  }

  PSTAGE(0, 0);
  asm volatile("s_waitcnt vmcnt(0)" ::: "memory");
  __builtin_amdgcn_sched_barrier(0);
  __builtin_amdgcn_s_barrier();
  __builtin_amdgcn_sched_barrier(0);

#pragma unroll
  for (int t = 0; t < 4; ++t) {
    bf16x8 bfr[8];
#pragma unroll
    for (int kk = 0; kk < 2; ++kk)
#pragma unroll
      for (int nf = 0; nf < 4; ++nf)
        bfr[kk * 4 + nf] = *(const bf16x8*)&wpk[
            ((size_t)((wid * 4 + nf) * 8 + (t * 2 + kk)) * 64 + lane) * 8];
    if (t + 1 < 4) PSTAGE((t + 1) & 1, t + 1);
    const u16* as = As[t & 1];
#pragma unroll
    for (int kk = 0; kk < 2; ++kk) {
      bf16x8 afr[4];
#pragma unroll
      for (int mf = 0; mf < 4; ++mf) {
        int ra = mf * 16 + (lane & 15);
        int cbb = (((kk * 4 + (lane >> 4)) ^ (ra & 7)) << 4);
        afr[mf] = *(const bf16x8*)&as[ra * 64 + (cbb >> 1)];
      }
#pragma unroll
      for (int mf = 0; mf < 4; ++mf)
#pragma unroll
        for (int nf = 0; nf < 4; ++nf)
          acc[mf][nf] = __builtin_amdgcn_mfma_f32_16x16x32_bf16(afr[mf], bfr[kk * 4 + nf], acc[mf][nf], 0, 0, 0);
    }
    asm volatile("s_waitcnt vmcnt(0)" ::: "memory");
    __builtin_amdgcn_sched_barrier(0);
    __builtin_amdgcn_s_barrier();
    __builtin_amdgcn_sched_barrier(0);
  }
#undef PSTAGE

  // residual + bias; write d_out; accumulate LN partials
#pragma unroll
  for (int mf = 0; mf < 4; ++mf) {
#pragma unroll
    for (int j = 0; j < 4; ++j) {
      int m = m0 + mf * 16 + (lane >> 4) * 4 + j;
      int gm = m_base + m;
      int b = gm >> 12, nn = (gm >> 6) & 63, s = gm & 63;
      int hw = (((s >> 3) << 3) + (nn >> 3)) * 64 + ((s & 7) << 3) + (nn & 7);
      size_t rowo = (((size_t)b << 12) + hw) * C_;
      float s1 = 0.f, s2 = 0.f;
#pragma unroll
      for (int nf = 0; nf < 4; ++nf) {
        int col = wid * 64 + nf * 16 + (lane & 15);
        float v = acc[mf][nf][j] + bias[col] + res[rowo + col];
        acc[mf][nf][j] = v;
        outF[rowo + col] = v;
        s1 += v; s2 += v * v;
      }
#pragma unroll
      for (int off = 1; off < 16; off <<= 1) {
        s1 += __shfl_xor(s1, off);
        s2 += __shfl_xor(s2, off);
      }
      if ((lane & 15) == 0) {
        int rr = mf * 16 + (lane >> 4) * 4 + j;
        red[rr][wid * 2] = s1;
        red[rr][wid * 2 + 1] = s2;
      }
    }
  }
  __syncthreads();

  // finish LN, write h2 bf16 (row = local token (b_rel, hw))
#pragma unroll
  for (int mf = 0; mf < 4; ++mf) {
#pragma unroll
    for (int j = 0; j < 4; ++j) {
      int rr = mf * 16 + (lane >> 4) * 4 + j;
      float sum = red[rr][0] + red[rr][2] + red[rr][4] + red[rr][6];
      float ssq = red[rr][1] + red[rr][3] + red[rr][5] + red[rr][7];
      float mean = sum * (1.0f / C_);
      float var = ssq * (1.0f / C_) - mean * mean;
      float rstd = rsqrtf(var + EPS_);
      int m = m0 + rr;
      int b_rel = m >> 12, nn = (m >> 6) & 63, s = m & 63;
      int hw = (((s >> 3) << 3) + (nn >> 3)) * 64 + ((s & 7) << 3) + (nn & 7);
      size_t ho = (((size_t)b_rel << 12) + hw) * C_;
#pragma unroll
      for (int nf = 0; nf < 4; ++nf) {
        int col = wid * 64 + nf * 16 + (lane & 15);
        float nv = (acc[mf][nf][j] - mean) * rstd * ln_w[col] + ln_b[col];
        h2[ho + col] = f2bf(nv);
      }
    }
  }
}

// ---------------------------------------------------------------------------
// MFMA attention, d0-split + chunked XCD swizzle. (round-15 structure)
__launch_bounds__(256)
__global__ void attn_mfma(const u16* __restrict__ qb, const u16* __restrict__ kb,
                          const u16* __restrict__ vt, const float* __restrict__ rel_bias,
                          u16* __restrict__ outp) {
  __shared__ u16 bufA[4096];   // Q tile, then P
  __shared__ u16 bufB[4096];   // K tile, then V tile
  int nb = gridDim.x;
  int cpx = nb >> 3;
  int swzb = (blockIdx.x & 7) * cpx + (blockIdx.x >> 3);
  int half = swzb & 1;
  int bh = swzb >> 1;          // b_rel*8 + h
  int h = bh & 7;
  int b_rel = bh >> 3;
  int tid = threadIdx.x;
  int w = tid >> 6, lane = tid & 63;
  int l3 = lane >> 3, l7 = lane & 7;
  const u16* qg = qb + (size_t)bh * 64 * 2048;
  const u16* kg = kb + (size_t)bh * 64 * 2048;
  const u16* vg = vt + (size_t)bh * 2048 * 64;

  // ---- phase 1: S = Q K^T ----
  f32x4 acc[4] = {};
  for (int k0 = 0; k0 < 2048; k0 += 64) {
#pragma unroll
    for (int r = 0; r < 2; ++r) {
      int row = w * 16 + r * 8 + l3;
      int sc = (l7 ^ (row & 7)) * 8;
      gload_lds16(qg + (size_t)row * 2048 + k0 + sc, &bufA[(w * 16 + r * 8) * 64]);
      gload_lds16(kg + (size_t)row * 2048 + k0 + sc, &bufB[(w * 16 + r * 8) * 64]);
    }
    __syncthreads();
    int rowq = w * 16 + (lane & 15);
#pragma unroll
    for (int ks = 0; ks < 2; ++ks) {
      bf16x8 aq = *(const bf16x8*)&bufA[rowq * 64 + (((ks * 4 + (lane >> 4)) ^ (rowq & 7)) << 3)];
#pragma unroll
      for (int cf = 0; cf < 4; ++cf) {
        int m = cf * 16 + (lane & 15);
        bf16x8 bk = *(const bf16x8*)&bufB[m * 64 + (((ks * 4 + (lane >> 4)) ^ (m & 7)) << 3)];
        acc[cf] = __builtin_amdgcn_mfma_f32_16x16x32_bf16(aq, bk, acc[cf], 0, 0, 0);
      }
    }
    __syncthreads();
  }

  // ---- phase 2: scale + rel bias + softmax ----
  const float scale = 0.17677669529663688f;   // 1/sqrt(32)
#pragma unroll
  for (int j = 0; j < 4; ++j) {
    int r = w * 16 + (lane >> 4) * 4 + j;
    int i1 = r >> 3, j1 = r & 7;
    float v[4];
#pragma unroll
    for (int cf = 0; cf < 4; ++cf) {
      int c = cf * 16 + (lane & 15);
      int idx = (i1 - (c >> 3) + 7) * 15 + (j1 - (c & 7) + 7);
      v[cf] = acc[cf][j] * scale + rel_bias[idx * NH_ + h];
    }
    float mx = fmaxf(fmaxf(v[0], v[1]), fmaxf(v[2], v[3]));
#pragma unroll
    for (int off = 8; off; off >>= 1) mx = fmaxf(mx, __shfl_xor(mx, off));
    float sm = 0.f;
#pragma unroll
    for (int cf = 0; cf < 4; ++cf) { v[cf] = __expf(v[cf] - mx); sm += v[cf]; }
#pragma unroll
    for (int off = 8; off; off >>= 1) sm += __shfl_xor(sm, off);
    float inv = 1.0f / sm;
#pragma unroll
    for (int cf = 0; cf < 4; ++cf) {
      int c = cf * 16 + (lane & 15);
      bufA[r * 64 + (c ^ ((r & 7) << 3))] = f2bf(v[cf] * inv);
    }
  }
  __syncthreads();

  bf16x8 pa[2];
  {
    int n = w * 16 + (lane & 15);
#pragma unroll
    for (int ks = 0; ks < 2; ++ks)
      pa[ks] = *(const bf16x8*)&bufA[n * 64 + ((ks * 32 + (lane >> 4) * 8) ^ ((n & 7) << 3))];
  }

  // ---- phase 3: O = P V (this block's d0 half only) ----
  int d0beg = half * 1024;
  for (int d0 = d0beg; d0 < d0beg + 1024; d0 += 64) {
#pragma unroll
    for (int r = 0; r < 2; ++r) {
      int drow = w * 16 + r * 8 + l3;
      int sc = (l7 ^ (drow & 7)) * 8;
      gload_lds16(vg + (size_t)(d0 + drow) * 64 + sc, &bufB[(w * 16 + r * 8) * 64]);
    }
    __syncthreads();
    f32x4 o[4] = {};
#pragma unroll
    for (int ks = 0; ks < 2; ++ks)
#pragma unroll
      for (int cf = 0; cf < 4; ++cf) {
        int d = cf * 16 + (lane & 15);
        bf16x8 bv = *(const bf16x8*)&bufB[d * 64 + (((ks * 4 + (lane >> 4)) ^ (d & 7)) << 3)];
        o[cf] = __builtin_amdgcn_mfma_f32_16x16x32_bf16(pa[ks], bv, o[cf], 0, 0, 0);
      }
#pragma unroll
    for (int cf = 0; cf < 4; ++cf) {
      int f = h * 2048 + d0 + cf * 16 + (lane & 15);
      int s = f >> 8, c = f & 255;
#pragma unroll
      for (int j = 0; j < 4; ++j) {
        int n = w * 16 + (lane >> 4) * 4 + j;
        outp[(((size_t)b_rel * 64 + n) * 64 + s) * 256 + c] = f2bf(o[cf][j]);
      }
    }
    __syncthreads();
  }
}

// ---------------------------------------------------------------------------
// Depthwise 3x3 SAME + bias + exact GELU — 4x2 pixel register tile + chunked
// XCD swizzle. (round-15 structure)
__launch_bounds__(256)
__global__ void dwconv_gelu(const u16* __restrict__ y1, const float* __restrict__ dw_w,
                            const float* __restrict__ dw_b, u16* __restrict__ y2) {
  int nb = gridDim.x;
  int cpx = nb >> 3;
  int bid = (blockIdx.x & 7) * cpx + (blockIdx.x >> 3);
  int wt = bid & 31, ht = (bid >> 5) & 15, b = bid >> 9;
  int h0 = ht * 4, w0 = wt * 2;
  int c0 = threadIdx.x * 4;

  float4 wv[9];
#pragma unroll
  for (int i = 0; i < 9; ++i) wv[i] = *(const float4*)&dw_w[i * HID_ + c0];

  ushort4 in[6][4];
#pragma unroll
  for (int ii = 0; ii < 6; ++ii) {
    int hh = h0 + ii - 1;
#pragma unroll
    for (int jj = 0; jj < 4; ++jj) {
      int ww = w0 + jj - 1;
      if ((unsigned)hh < 64u && (unsigned)ww < 64u)
        in[ii][jj] = *(const ushort4*)(y1 + ((size_t)((b << 12) + hh * 64 + ww)) * HID_ + c0);
      else
        in[ii][jj] = ushort4{0, 0, 0, 0};
    }
  }

  float4 bv = *(const float4*)&dw_b[c0];
  float4 acc[4][2];
#pragma unroll
  for (int i = 0; i < 4; ++i)
#pragma unroll
    for (int j = 0; j < 2; ++j) acc[i][j] = bv;

#pragma unroll
  for (int ii = 0; ii < 6; ++ii) {
#pragma unroll
    for (int jj = 0; jj < 4; ++jj) {
      ushort4 u = in[ii][jj];
      float4 f = {bf2f(u.x), bf2f(u.y), bf2f(u.z), bf2f(u.w)};
#pragma unroll
      for (int kh = 0; kh < 3; ++kh) {
        int i = ii - kh;
        if (i < 0 || i > 3) continue;
#pragma unroll
        for (int kw = 0; kw < 3; ++kw) {
          int j = jj - kw;
          if (j < 0 || j > 1) continue;
          float4 w4 = wv[kh * 3 + kw];
          acc[i][j].x += f.x * w4.x;
          acc[i][j].y += f.y * w4.y;
          acc[i][j].z += f.z * w4.z;
          acc[i][j].w += f.w * w4.w;
        }
      }
    }
  }

  const float k = 0.70710678118654752f;
#pragma unroll
  for (int i = 0; i < 4; ++i) {
#pragma unroll
    for (int j = 0; j < 2; ++j) {
      float4 a = acc[i][j];
      ushort4 o;
      o.x = f2bf(0.5f * a.x * (1.0f + erff(a.x * k)));
      o.y = f2bf(0.5f * a.y * (1.0f + erff(a.y * k)));
      o.z = f2bf(0.5f * a.z * (1.0f + erff(a.z * k)));
      o.w = f2bf(0.5f * a.w * (1.0f + erff(a.w * k)));
      *(ushort4*)(y2 + ((size_t)((b << 12) + (h0 + i) * 64 + (w0 + j))) * HID_ + c0) = o;
    }
  }
}

// ---------------------------------------------------------------------------
extern "C" void kernel_launch(void* const* d_in, const int* in_sizes, int n_in,
                              void* d_out, int out_size, void* d_ws, size_t ws_size,
                              hipStream_t stream) {
  const float* x       = (const float*)d_in[0];
  const float* norm1_w = (const float*)d_in[1];
  const float* norm1_b = (const float*)d_in[2];
  const float* qkv_w   = (const float*)d_in[3];
  const float* qkv_b   = (const float*)d_in[4];
  const float* rel_b   = (const float*)d_in[5];
  const float* proj_w  = (const float*)d_in[6];
  const float* proj_b  = (const float*)d_in[7];
  const float* norm2_w = (const float*)d_in[8];
  const float* norm2_b = (const float*)d_in[9];
  const float* fc1_w   = (const float*)d_in[10];
  const float* fc1_b   = (const float*)d_in[11];
  const float* dw_w    = (const float*)d_in[12];
  const float* dw_b    = (const float*)d_in[13];
  const float* fc2_w   = (const float*)d_in[14];
  const float* fc2_b   = (const float*)d_in[15];
  float* out = (float*)d_out;
  char* ws = (char*)d_ws;

  // --- packed-weight slab: first 2 MB of ws ---
  u16* wq = (u16*)(ws);                       // 768*256
  u16* wp = wq + 768 * 256;                   // 256*256
  u16* w1 = wp + 256 * 256;                   // 1024*256
  u16* w2 = w1 + 1024 * 256;                  // 256*1024
  pack_w_kernel<<<768 * 256 / 8 / 256, 256, 0, stream>>>(qkv_w, wq, 256, 3);
  pack_w_kernel<<<256 * 256 / 8 / 256, 256, 0, stream>>>(proj_w, wp, 256, 3);
  pack_w_kernel<<<1024 * 256 / 8 / 256, 256, 0, stream>>>(fc1_w, w1, 256, 3);
  pack_w_kernel<<<256 * 1024 / 8 / 256, 256, 0, stream>>>(fc2_w, w2, 1024, 5);

  // --- adaptive chunking over batches; chunk workspace = 18*G MB after 2 MB ---
  const size_t MBy = (size_t)1 << 20;
  char* cws = ws + 2 * MBy;
  int G = 1;
  for (int g = 16; g >= 1; g >>= 1) {
    if (2 * MBy + (size_t)(18 * g) * MBy <= ws_size) { G = g; break; }
  }
  const size_t gm = (size_t)G * MBy;
  u16* h1c    = (u16*)(cws);                 // 2G MB
  u16* qbuf   = (u16*)(cws + 2 * gm);        // 2G MB  [bh][n][2048]
  u16* kbuf   = (u16*)(cws + 4 * gm);        // 2G MB  [bh][m][2048]
  u16* vtbuf  = (u16*)(cws + 6 * gm);        // 2G MB  [bh][d][64]
  u16* attnoc = (u16*)(cws + 8 * gm);        // 2G MB
  u16* h2c    = (u16*)(cws);                 // 2G MB (over dead h1c)
  u16* y1c    = (u16*)(cws + 2 * gm);        // 8G MB (over dead q/k/vt)
  u16* y2c    = (u16*)(cws + 10 * gm);       // 8G MB

  const int Mloc = G * 4096;
  for (int b0 = 0; b0 < B_; b0 += G) {
    ln_kernel<<<Mloc / 4, 256, 0, stream>>>(x, norm1_w, norm1_b, h1c, b0);
    gemm_mfma<256, 768, 3><<<dim3(6, Mloc / 128), 256, 0, stream>>>(
        h1c, wq, qkv_b, nullptr, nullptr, nullptr, 0, qbuf, kbuf, vtbuf);
    attn_mfma<<<G * 16, 256, 0, stream>>>(qbuf, kbuf, vtbuf, rel_b, attnoc);
    proj_ln_fused<<<Mloc / 64, 256, 0, stream>>>(
        attnoc, wp, proj_b, x, out, norm2_w, norm2_b, h2c, b0 * 4096);
    gemm_mfma<256, 1024, 0><<<dim3(8, Mloc / 128), 256, 0, stream>>>(
        h2c, w1, fc1_b, y1c, nullptr, nullptr, 0, nullptr, nullptr, nullptr);
    dwconv_gelu<<<Mloc / 8, 256, 0, stream>>>(y1c, dw_w, dw_b, y2c);
    gemm_mfma<1024, 256, 2><<<dim3(2, Mloc / 128), 256, 0, stream>>>(
        y2c, w2, fc2_b, nullptr, out, nullptr, b0 * 4096, nullptr, nullptr, nullptr);
  }
}